// Round 3
// baseline (277.849 us; speedup 1.0000x reference)
//
#include <hip/hip_runtime.h>
#include <cstddef>

#define BB   256   // batch
#define UU   8     // in_units
#define ISZ  1152  // in_size
#define JJ   10    // out_units
#define DD   16    // out_size
#define JD   (JJ*DD)        // 160
#define NCH  72             // i-chunks in s kernel
#define ICH  16
#define NCA  144            // i-chunks in agreement kernel
#define ICA  8
#define WROW (JJ*DD*UU)     // 1280 floats per i row of W

// ---------------- transpose: x[b,u,i] -> xT[u,i,b]; also init b_ij=1 ----------------
__global__ void transpose_x(const float* __restrict__ x, float* __restrict__ xT,
                            float* __restrict__ b_ij) {
    __shared__ float tile[64][65];
    int it = blockIdx.x;          // 18 tiles of 64 i
    int bt = blockIdx.y;          // 4 tiles of 64 b
    int u  = blockIdx.z;          // 8
    int lane = threadIdx.x & 63;
    int w    = threadIdx.x >> 6;  // 0..3
    // fold b_ij init into the first 45 blocks (11520 = 45*256)
    int flat = (blockIdx.z * 4 + blockIdx.y) * 18 + blockIdx.x;
    if (flat < 45) b_ij[flat * 256 + threadIdx.x] = 1.0f;
#pragma unroll
    for (int r = 0; r < 16; ++r) {
        int b = bt * 64 + w * 16 + r;
        int i = it * 64 + lane;
        tile[w * 16 + r][lane] = x[(size_t)b * (UU * ISZ) + (size_t)u * ISZ + i];
    }
    __syncthreads();
#pragma unroll
    for (int r = 0; r < 16; ++r) {
        int i = it * 64 + w * 16 + r;
        int b = bt * 64 + lane;
        xT[((size_t)u * ISZ + i) * BB + b] = tile[lane][w * 16 + r];
    }
}

// ---------------- s step with fused softmax ----------------
// grid (NCH, 2, JJ), block 256 = all 256 b.
// W/b_ij addresses wave-uniform -> s_load. Partials: s_part[ic][b][j*16+dh*8+dd]
__global__ __launch_bounds__(256) void s_kernel(
        const float* __restrict__ xT, const float* __restrict__ W,
        const float* __restrict__ b_ij, float* __restrict__ s_part, int first) {
    int ic = blockIdx.x;
    int dh = blockIdx.y;   // 0..1, 8 d's each
    int j  = blockIdx.z;
    int t  = threadIdx.x;
    int lane = t & 63, wv = t >> 6;
    __shared__ float c_lds[ICH];
    __shared__ float redm[4];
    __shared__ float reds[4];
    int i0 = ic * ICH;

    if (first) {
        if (t < ICH) c_lds[t] = 1.0f / 1152.0f;   // softmax of uniform b
    } else {
        // softmax over all i for this j (redundant per block; cheap)
        float m = -1e30f;
        for (int idx = t; idx < ISZ; idx += 256) m = fmaxf(m, b_ij[j * ISZ + idx]);
#pragma unroll
        for (int off = 32; off; off >>= 1) m = fmaxf(m, __shfl_down(m, off, 64));
        if (lane == 0) redm[wv] = m;
        __syncthreads();
        m = fmaxf(fmaxf(redm[0], redm[1]), fmaxf(redm[2], redm[3]));
        float ssum = 0.f;
        for (int idx = t; idx < ISZ; idx += 256) ssum += expf(b_ij[j * ISZ + idx] - m);
#pragma unroll
        for (int off = 32; off; off >>= 1) ssum += __shfl_down(ssum, off, 64);
        if (lane == 0) reds[wv] = ssum;
        __syncthreads();
        float inv = 1.f / (reds[0] + reds[1] + reds[2] + reds[3]);
        if (t < ICH) c_lds[t] = expf(b_ij[j * ISZ + i0 + t] - m) * inv;
    }
    __syncthreads();

    int b = t;
    float acc[8] = {0.f, 0.f, 0.f, 0.f, 0.f, 0.f, 0.f, 0.f};
#pragma unroll
    for (int ii = 0; ii < ICH; ++ii) {
        int i = i0 + ii;
        float xv[8];
#pragma unroll
        for (int u = 0; u < 8; ++u) xv[u] = xT[((size_t)u * ISZ + i) * BB + b];
        float ci = c_lds[ii];
        const float* Wp = W + (size_t)i * WROW + j * (DD * UU) + dh * (8 * UU);
#pragma unroll
        for (int dd = 0; dd < 8; ++dd) {
            float s = 0.f;
#pragma unroll
            for (int u = 0; u < 8; ++u) s += Wp[dd * 8 + u] * xv[u];   // s_load (uniform)
            acc[dd] += ci * s;
        }
    }
    size_t base = ((size_t)ic * BB + b) * JD + j * DD + dh * 8;
#pragma unroll
    for (int dd = 0; dd < 8; ++dd) s_part[base + dd] = acc[dd];
}

// ---------------- reduce partials + squash; v[b][j*16+d] ----------------
__global__ void reduce_squash_kernel(const float* __restrict__ s_part,
                                     float* __restrict__ v) {
    int b = blockIdx.x;
    int t = threadIdx.x;   // 192 threads, t<160 active
    __shared__ float sm[JD];
    float s = 0.f;
    if (t < JD) {
#pragma unroll 8
        for (int ic = 0; ic < NCH; ++ic) s += s_part[((size_t)ic * BB + b) * JD + t];
        sm[t] = s;
    }
    __syncthreads();
    if (t < JD) {
        int d = t & 15;
        float msq = 0.f;
#pragma unroll
        for (int j = 0; j < JJ; ++j) { float x = sm[j * DD + d]; msq += x * x; }
        float inv = rsqrtf(msq);
        v[b * JD + t] = msq / (1.f + msq) * s * inv;
    }
}

// ---------------- agreement: b_ij[j][i] += (1/B) sum_{b,d} u_hat * v ----------------
// grid (NCA, JJ), block 256 = all b. W scalar loads (uniform); vv[16] per-thread regs.
__global__ __launch_bounds__(256) void agreement_kernel(
        const float* __restrict__ xT, const float* __restrict__ W,
        const float* __restrict__ v, float* __restrict__ b_ij) {
    int ic = blockIdx.x;
    int j  = blockIdx.y;
    int b  = threadIdx.x;
    int lane = b & 63, wv = b >> 6;
    float vv[16];
#pragma unroll
    for (int d = 0; d < 16; ++d) vv[d] = v[b * JD + j * DD + d];
    float acc[ICA];
    int i0 = ic * ICA;
#pragma unroll
    for (int ii = 0; ii < ICA; ++ii) {
        int i = i0 + ii;
        float xv[8];
#pragma unroll
        for (int u = 0; u < 8; ++u) xv[u] = xT[((size_t)u * ISZ + i) * BB + b];
        const float* Wp = W + (size_t)i * WROW + j * (DD * UU);
        float sum = 0.f;
#pragma unroll
        for (int d = 0; d < 16; ++d) {
            float tmp = 0.f;
#pragma unroll
            for (int u = 0; u < 8; ++u) tmp += Wp[d * 8 + u] * xv[u];  // s_load (uniform)
            sum += tmp * vv[d];
        }
        acc[ii] = sum;
    }
    __shared__ float red[4][ICA];
#pragma unroll
    for (int ii = 0; ii < ICA; ++ii) {
        float a = acc[ii];
#pragma unroll
        for (int off = 32; off; off >>= 1) a += __shfl_down(a, off, 64);
        if (lane == 0) red[wv][ii] = a;
    }
    __syncthreads();
    if (b < ICA) {
        float r = red[0][b] + red[1][b] + red[2][b] + red[3][b];
        b_ij[j * ISZ + i0 + b] += r * (1.0f / (float)BB);
    }
}

extern "C" void kernel_launch(void* const* d_in, const int* in_sizes, int n_in,
                              void* d_out, int out_size, void* d_ws, size_t ws_size,
                              hipStream_t stream) {
    const float* x = (const float*)d_in[0];   // (256, 8, 1152)
    const float* W = (const float*)d_in[1];   // (1, 1152, 10, 16, 8)
    float* out = (float*)d_out;               // (256, 10, 16, 1) -> v

    float* xT     = (float*)d_ws;                  // 8*1152*256 = 2,359,296 floats
    float* b_ij   = xT + (size_t)UU * ISZ * BB;    // 11,520
    float* s_part = b_ij + ISZ * JJ;               // 72*256*160 = 2,949,120 floats
    float* v      = out;                           // v lives in d_out

    hipLaunchKernelGGL(transpose_x, dim3(18, 4, 8), dim3(256), 0, stream, x, xT, b_ij);

    for (int it = 0; it < 3; ++it) {
        hipLaunchKernelGGL(s_kernel, dim3(NCH, 2, JJ), dim3(256), 0, stream,
                           xT, W, b_ij, s_part, it == 0 ? 1 : 0);
        hipLaunchKernelGGL(reduce_squash_kernel, dim3(BB), dim3(192), 0, stream,
                           s_part, v);
        if (it < 2) {
            hipLaunchKernelGGL(agreement_kernel, dim3(NCA, JJ), dim3(256), 0, stream,
                               xT, W, v, b_ij);
        }
    }
}